// Round 1
// baseline (782.116 us; speedup 1.0000x reference)
//
#include <hip/hip_runtime.h>
#include <cstddef>

#define HW 4096

// ---------------- K1: LayerNorm + fc1/fc2 + pooled K/V ----------------
__global__ __launch_bounds__(256) void k1_ln_fc(
    const float* __restrict__ x, const float* __restrict__ ng, const float* __restrict__ nb,
    const float* __restrict__ w1, const float* __restrict__ b1,
    const float* __restrict__ w2, const float* __restrict__ b2,
    float* __restrict__ gq, float* __restrict__ gkp, float* __restrict__ gvp,
    float* __restrict__ lqi, float* __restrict__ lki, float* __restrict__ lvi)
{
    __shared__ float xn[128][64];
    __shared__ float red[2][4][64];
    const int t = threadIdx.x;
    const int g = t >> 6;
    const int p = t & 63;
    const int bx = blockIdx.x;
    const int b = bx >> 6;
    const int h = bx & 63;
    const float* xrow = x + (size_t)b * 128 * HW + h * 64;
    float s1 = 0.f, s2 = 0.f;
    #pragma unroll
    for (int i = 0; i < 32; ++i) {
        int c = g * 32 + i;
        float v = xrow[(size_t)c * HW + p];
        xn[c][p] = v;
        s1 += v; s2 += v * v;
    }
    red[0][g][p] = s1; red[1][g][p] = s2;
    __syncthreads();
    float m   = (red[0][0][p] + red[0][1][p] + red[0][2][p] + red[0][3][p]) * (1.f / 128.f);
    float var = (red[1][0][p] + red[1][1][p] + red[1][2][p] + red[1][3][p]) * (1.f / 128.f) - m * m;
    float rstd = rsqrtf(var + 1e-5f);
    #pragma unroll
    for (int i = 0; i < 32; ++i) {
        int c = g * 32 + i;
        float v = xn[c][p];
        xn[c][p] = (v - m) * rstd * ng[c] + nb[c];
    }
    __syncthreads();

    const int gu = __builtin_amdgcn_readfirstlane(g);
    const size_t sp = (size_t)h * 64 + p;

    float acc[16];
    auto gemm16 = [&](const float* __restrict__ wmat, const float* __restrict__ bias,
                      int obase, int ibase) {
        #pragma unroll
        for (int r = 0; r < 16; ++r) acc[r] = bias[obase + gu + 4 * r];
        #pragma unroll 4
        for (int i = 0; i < 64; ++i) {
            float xv = xn[ibase + i][p];
            #pragma unroll
            for (int r = 0; r < 16; ++r)
                acc[r] = fmaf(wmat[(size_t)(obase + gu + 4 * r) * 64 + i], xv, acc[r]);
        }
    };

    // fc2 -> local qkv conv inputs, layout [b][lh][cl][h][w]
    for (int cc = 0; cc < 3; ++cc) {
        gemm16(w2, b2, 64 * cc, 0);
        float* dst = (cc == 0) ? lqi : (cc == 1) ? lki : lvi;
        #pragma unroll
        for (int r = 0; r < 16; ++r) {
            int ch = gu + 4 * r;   // lh*16+cl
            dst[(((size_t)b * 4 + (ch >> 4)) * 16 + (ch & 15)) * HW + sp] = acc[r];
        }
    }
    // fc1 q -> gq, layout [b][gh][cg][n]
    gemm16(w1, b1, 0, 64);
    #pragma unroll
    for (int r = 0; r < 16; ++r) {
        int ch = gu + 4 * r;       // gh*16+cg
        gq[(((size_t)b * 4 + (ch >> 4)) * 16 + (ch & 15)) * HW + sp] = acc[r];
    }
    // fc1 k,v -> pooled via 8-lane reduce + atomicAdd (layout [b][gh][m][cg])
    const int m2 = (h >> 3) * 8 + (p >> 3);
    for (int cc = 4; cc <= 5; ++cc) {
        gemm16(w1, b1, 64 * (cc - 3), 64);
        float* dst = (cc == 4) ? gkp : gvp;
        #pragma unroll
        for (int r = 0; r < 16; ++r) {
            float v = acc[r];
            v += __shfl_xor(v, 1);
            v += __shfl_xor(v, 2);
            v += __shfl_xor(v, 4);
            if ((p & 7) == 0) {
                int ch = gu + 4 * r;
                atomicAdd(&dst[(((size_t)b * 4 + (ch >> 4)) * 64 + m2) * 16 + (ch & 15)],
                          v * (1.f / 64.f));
            }
        }
    }
}

// ---------------- K2: global attention (64 pooled tokens) ----------------
__global__ __launch_bounds__(256) void k2_attn(
    const float* __restrict__ gq, const float* __restrict__ gkp,
    const float* __restrict__ gvp, float* __restrict__ out)
{
    const int t = threadIdx.x;
    const int bx = blockIdx.x;
    const int tile = bx & 15;
    const int bg = bx >> 4;        // b*4+gh
    const int b = bg >> 2;
    const int gh = bg & 3;
    const int n = tile * 256 + t;
    const float* qp = gq + (size_t)bg * 16 * HW + n;
    float q[16];
    #pragma unroll
    for (int cg = 0; cg < 16; ++cg) q[cg] = qp[(size_t)cg * HW] * 0.125f;  // GD^-0.5
    const float* kbase = gkp + (size_t)bg * 64 * 16;
    float s[64];
    #pragma unroll
    for (int mm = 0; mm < 64; ++mm) {
        const float* kr = kbase + mm * 16;   // block-uniform address -> s_load
        float a = 0.f;
        #pragma unroll
        for (int cg = 0; cg < 16; ++cg) a = fmaf(q[cg], kr[cg], a);
        s[mm] = a;
    }
    float mx = s[0];
    #pragma unroll
    for (int mm = 1; mm < 64; ++mm) mx = fmaxf(mx, s[mm]);
    float sum = 0.f;
    #pragma unroll
    for (int mm = 0; mm < 64; ++mm) { float e = __expf(s[mm] - mx); s[mm] = e; sum += e; }
    const float rs = 1.f / sum;
    const float* vbase = gvp + (size_t)bg * 64 * 16;
    float acc[16];
    #pragma unroll
    for (int cg = 0; cg < 16; ++cg) acc[cg] = 0.f;
    #pragma unroll
    for (int mm = 0; mm < 64; ++mm) {
        const float pm = s[mm];
        const float* vr = vbase + mm * 16;
        #pragma unroll
        for (int cg = 0; cg < 16; ++cg) acc[cg] = fmaf(pm, vr[cg], acc[cg]);
    }
    float* op = out + ((size_t)b * 128 + 64 + gh * 16) * HW + n;   // xg at channels 64..127
    #pragma unroll
    for (int cg = 0; cg < 16; ++cg) op[(size_t)cg * HW] = acc[cg] * rs;
}

// ---------------- K3: local branch (dwconv3x3 + gated mix) ----------------
__global__ __launch_bounds__(256) void k3_local(
    const float* __restrict__ lqi, const float* __restrict__ lki, const float* __restrict__ lvi,
    const float* __restrict__ qw, const float* __restrict__ qb,
    const float* __restrict__ kw, const float* __restrict__ kb,
    const float* __restrict__ vw, const float* __restrict__ vb,
    const float* __restrict__ w3, const float* __restrict__ b3,
    const float* __restrict__ w4, const float* __restrict__ b4,
    float* __restrict__ out)
{
    const int t = threadIdx.x;
    const int w = t & 63;          // full row per wave -> shfl for w+-1
    const int rr = t >> 6;
    const int bx = blockIdx.x;
    const int htile = bx & 15;
    const int bl = bx >> 4;        // b*4+lh
    const int b = bl >> 2;
    const int lh = bl & 3;
    const int h = htile * 4 + rr;
    const int lane_l = (w == 0) ? 0 : w - 1;
    const int lane_r = (w == 63) ? 63 : w + 1;
    float a[16], lvv[16];
    #pragma unroll
    for (int cl = 0; cl < 16; ++cl) {
        const size_t base = ((size_t)bl * 16 + cl) * HW;
        float aq = qb[cl], ak = kb[cl], av = vb[cl];
        #pragma unroll
        for (int dy = 0; dy < 3; ++dy) {
            const int hy = h + dy - 1;
            float xq = 0.f, xk = 0.f, xv = 0.f;
            if (hy >= 0 && hy < 64) {
                const size_t idx = base + (size_t)hy * 64 + w;
                xq = lqi[idx]; xk = lki[idx]; xv = lvi[idx];
            }
            float xql = __shfl(xq, lane_l); if (w == 0)  xql = 0.f;
            float xqr = __shfl(xq, lane_r); if (w == 63) xqr = 0.f;
            float xkl = __shfl(xk, lane_l); if (w == 0)  xkl = 0.f;
            float xkr = __shfl(xk, lane_r); if (w == 63) xkr = 0.f;
            float xvl = __shfl(xv, lane_l); if (w == 0)  xvl = 0.f;
            float xvr = __shfl(xv, lane_r); if (w == 63) xvr = 0.f;
            aq += qw[cl*9 + dy*3 + 0]*xql + qw[cl*9 + dy*3 + 1]*xq + qw[cl*9 + dy*3 + 2]*xqr;
            ak += kw[cl*9 + dy*3 + 0]*xkl + kw[cl*9 + dy*3 + 1]*xk + kw[cl*9 + dy*3 + 2]*xkr;
            av += vw[cl*9 + dy*3 + 0]*xvl + vw[cl*9 + dy*3 + 1]*xv + vw[cl*9 + dy*3 + 2]*xvr;
        }
        a[cl] = aq * ak;
        lvv[cl] = av;
    }
    float a2[16];
    #pragma unroll
    for (int o = 0; o < 16; ++o) {
        float acc = b3[o];
        #pragma unroll
        for (int c2 = 0; c2 < 16; ++c2) acc = fmaf(w3[o*16 + c2], a[c2], acc);
        a2[o] = acc / (1.f + __expf(-acc));    // silu
    }
    float* op = out + ((size_t)b * 128 + lh * 16) * HW + (size_t)h * 64 + w;  // xl at ch 0..63
    #pragma unroll
    for (int o = 0; o < 16; ++o) {
        float acc = b4[o];
        #pragma unroll
        for (int c2 = 0; c2 < 16; ++c2) acc = fmaf(w4[o*16 + c2], a2[c2], acc);
        float th = tanhf(acc * 8.f);           // tanh(a / LD^-0.5)
        op[(size_t)o * HW] = th * lvv[o];
    }
}

// ---------------- K4: fc5 (128x128) + residual, in-place on d_out ----------------
__global__ __launch_bounds__(256) void k4_fc5(
    const float* __restrict__ x, const float* __restrict__ w5,
    const float* __restrict__ b5, float* __restrict__ out)
{
    __shared__ float xc[128][64];
    const int t = threadIdx.x;
    const int g = t >> 6;
    const int p = t & 63;
    const int bx = blockIdx.x;
    const int b = bx >> 6;
    const int h = bx & 63;
    float* obase = out + (size_t)b * 128 * HW + h * 64;
    #pragma unroll
    for (int i = 0; i < 32; ++i) {
        int c = g * 32 + i;
        xc[c][p] = obase[(size_t)c * HW + p];
    }
    __syncthreads();
    const int gu = __builtin_amdgcn_readfirstlane(g);
    const float* xrow = x + (size_t)b * 128 * HW + h * 64;
    for (int cc = 0; cc < 2; ++cc) {
        float acc[16];
        #pragma unroll
        for (int r = 0; r < 16; ++r) acc[r] = b5[gu + 64 * cc + 4 * r];
        #pragma unroll 4
        for (int i = 0; i < 128; ++i) {
            float xv = xc[i][p];
            #pragma unroll
            for (int r = 0; r < 16; ++r)
                acc[r] = fmaf(w5[(size_t)(gu + 64 * cc + 4 * r) * 128 + i], xv, acc[r]);
        }
        #pragma unroll
        for (int r = 0; r < 16; ++r) {
            const int o = gu + 64 * cc + 4 * r;
            obase[(size_t)o * HW + p] = xrow[(size_t)o * HW + p] + acc[r];
        }
    }
}

extern "C" void kernel_launch(void* const* d_in, const int* in_sizes, int n_in,
                              void* d_out, int out_size, void* d_ws, size_t ws_size,
                              hipStream_t stream) {
    const float* x  = (const float*)d_in[0];
    const float* ng = (const float*)d_in[1];
    const float* nb = (const float*)d_in[2];
    const float* w1 = (const float*)d_in[3];
    const float* b1 = (const float*)d_in[4];
    const float* w2 = (const float*)d_in[5];
    const float* b2 = (const float*)d_in[6];
    const float* qw = (const float*)d_in[7];
    const float* qb = (const float*)d_in[8];
    const float* kw = (const float*)d_in[9];
    const float* kb = (const float*)d_in[10];
    const float* vw = (const float*)d_in[11];
    const float* vb = (const float*)d_in[12];
    const float* w3 = (const float*)d_in[13];
    const float* b3 = (const float*)d_in[14];
    const float* w4 = (const float*)d_in[15];
    const float* b4 = (const float*)d_in[16];
    const float* w5 = (const float*)d_in[17];
    const float* b5 = (const float*)d_in[18];
    float* out = (float*)d_out;
    float* ws  = (float*)d_ws;

    float* gq  = ws;                    // 8388608 floats  [b][gh][cg][n]
    float* gkp = gq  + 8388608;         // 131072          [b][gh][m][cg]
    float* gvp = gkp + 131072;          // 131072
    float* lqi = gvp + 131072;          // 8388608         [b][lh][cl][h][w]
    float* lki = lqi + 8388608;
    float* lvi = lki + 8388608;

    hipMemsetAsync(gkp, 0, 2 * 131072 * sizeof(float), stream);
    k1_ln_fc<<<2048, 256, 0, stream>>>(x, ng, nb, w1, b1, w2, b2,
                                       gq, gkp, gvp, lqi, lki, lvi);
    k2_attn<<<2048, 256, 0, stream>>>(gq, gkp, gvp, out);
    k3_local<<<2048, 256, 0, stream>>>(lqi, lki, lvi, qw, qb, kw, kb, vw, vb,
                                       w3, b3, w4, b4, out);
    k4_fc5<<<2048, 256, 0, stream>>>(x, w5, b5, out);
}

// Round 2
// 706.147 us; speedup vs baseline: 1.1076x; 1.1076x over previous
//
#include <hip/hip_runtime.h>
#include <cstddef>

#define HW 4096

// ---------------- K1: LayerNorm + fc1/fc2 + pooled K/V ----------------
__global__ __launch_bounds__(256) void k1_ln_fc(
    const float* __restrict__ x, const float* __restrict__ ng, const float* __restrict__ nb,
    const float* __restrict__ w1, const float* __restrict__ b1,
    const float* __restrict__ w2, const float* __restrict__ b2,
    float* __restrict__ gq, float* __restrict__ gkp, float* __restrict__ gvp,
    float* __restrict__ lqi, float* __restrict__ lki, float* __restrict__ lvi)
{
    __shared__ float xn[128][64];
    __shared__ float red[2][4][64];
    const int t = threadIdx.x;
    const int g = t >> 6;
    const int p = t & 63;
    const int bx = blockIdx.x;
    const int b = bx >> 6;
    const int h = bx & 63;
    const float* xrow = x + (size_t)b * 128 * HW + h * 64;
    float s1 = 0.f, s2 = 0.f;
    #pragma unroll
    for (int i = 0; i < 32; ++i) {
        int c = g * 32 + i;
        float v = xrow[(size_t)c * HW + p];
        xn[c][p] = v;
        s1 += v; s2 += v * v;
    }
    red[0][g][p] = s1; red[1][g][p] = s2;
    __syncthreads();
    float m   = (red[0][0][p] + red[0][1][p] + red[0][2][p] + red[0][3][p]) * (1.f / 128.f);
    float var = (red[1][0][p] + red[1][1][p] + red[1][2][p] + red[1][3][p]) * (1.f / 128.f) - m * m;
    float rstd = rsqrtf(var + 1e-5f);
    #pragma unroll
    for (int i = 0; i < 32; ++i) {
        int c = g * 32 + i;
        float v = xn[c][p];
        xn[c][p] = (v - m) * rstd * ng[c] + nb[c];
    }
    __syncthreads();

    const int gu = __builtin_amdgcn_readfirstlane(g);
    const size_t sp = (size_t)h * 64 + p;

    float acc[16];
    auto gemm16 = [&](const float* __restrict__ wmat, const float* __restrict__ bias,
                      int obase, int ibase) {
        #pragma unroll
        for (int r = 0; r < 16; ++r) acc[r] = bias[obase + gu + 4 * r];
        #pragma unroll 4
        for (int i = 0; i < 64; ++i) {
            float xv = xn[ibase + i][p];
            #pragma unroll
            for (int r = 0; r < 16; ++r)
                acc[r] = fmaf(wmat[(size_t)(obase + gu + 4 * r) * 64 + i], xv, acc[r]);
        }
    };

    // fc2 -> local qkv conv inputs, layout [b][lh][cl][h][w]
    for (int cc = 0; cc < 3; ++cc) {
        gemm16(w2, b2, 64 * cc, 0);
        float* dst = (cc == 0) ? lqi : (cc == 1) ? lki : lvi;
        #pragma unroll
        for (int r = 0; r < 16; ++r) {
            int ch = gu + 4 * r;   // lh*16+cl
            dst[(((size_t)b * 4 + (ch >> 4)) * 16 + (ch & 15)) * HW + sp] = acc[r];
        }
    }
    // fc1 q -> gq, layout [b][gh][cg][n]
    gemm16(w1, b1, 0, 64);
    #pragma unroll
    for (int r = 0; r < 16; ++r) {
        int ch = gu + 4 * r;       // gh*16+cg
        gq[(((size_t)b * 4 + (ch >> 4)) * 16 + (ch & 15)) * HW + sp] = acc[r];
    }
    // fc1 k,v -> pooled via 8-lane reduce + atomicAdd (layout [b][gh][m][cg])
    const int m2 = (h >> 3) * 8 + (p >> 3);
    for (int cc = 4; cc <= 5; ++cc) {
        gemm16(w1, b1, 64 * (cc - 3), 64);
        float* dst = (cc == 4) ? gkp : gvp;
        #pragma unroll
        for (int r = 0; r < 16; ++r) {
            float v = acc[r];
            v += __shfl_xor(v, 1);
            v += __shfl_xor(v, 2);
            v += __shfl_xor(v, 4);
            if ((p & 7) == 0) {
                int ch = gu + 4 * r;
                atomicAdd(&dst[(((size_t)b * 4 + (ch >> 4)) * 64 + m2) * 16 + (ch & 15)],
                          v * (1.f / 64.f));
            }
        }
    }
}

// ---------------- K2: global attention (64 pooled tokens) ----------------
__global__ __launch_bounds__(256) void k2_attn(
    const float* __restrict__ gq, const float* __restrict__ gkp,
    const float* __restrict__ gvp, float* __restrict__ out)
{
    const int t = threadIdx.x;
    const int bx = blockIdx.x;
    const int tile = bx & 15;
    const int bg = bx >> 4;        // b*4+gh
    const int b = bg >> 2;
    const int gh = bg & 3;
    const int n = tile * 256 + t;
    const float* qp = gq + (size_t)bg * 16 * HW + n;
    float q[16];
    #pragma unroll
    for (int cg = 0; cg < 16; ++cg) q[cg] = qp[(size_t)cg * HW] * 0.125f;  // GD^-0.5
    const float* kbase = gkp + (size_t)bg * 64 * 16;
    float s[64];
    #pragma unroll
    for (int mm = 0; mm < 64; ++mm) {
        const float* kr = kbase + mm * 16;   // block-uniform address -> s_load
        float a = 0.f;
        #pragma unroll
        for (int cg = 0; cg < 16; ++cg) a = fmaf(q[cg], kr[cg], a);
        s[mm] = a;
    }
    float mx = s[0];
    #pragma unroll
    for (int mm = 1; mm < 64; ++mm) mx = fmaxf(mx, s[mm]);
    float sum = 0.f;
    #pragma unroll
    for (int mm = 0; mm < 64; ++mm) { float e = __expf(s[mm] - mx); s[mm] = e; sum += e; }
    const float rs = 1.f / sum;
    const float* vbase = gvp + (size_t)bg * 64 * 16;
    float acc[16];
    #pragma unroll
    for (int cg = 0; cg < 16; ++cg) acc[cg] = 0.f;
    #pragma unroll
    for (int mm = 0; mm < 64; ++mm) {
        const float pm = s[mm];
        const float* vr = vbase + mm * 16;
        #pragma unroll
        for (int cg = 0; cg < 16; ++cg) acc[cg] = fmaf(pm, vr[cg], acc[cg]);
    }
    float* op = out + ((size_t)b * 128 + 64 + gh * 16) * HW + n;   // xg at channels 64..127
    #pragma unroll
    for (int cg = 0; cg < 16; ++cg) op[(size_t)cg * HW] = acc[cg] * rs;
}

// ---------------- K3: local branch (dwconv3x3 + gated mix), LDS halo tiles ----------------
__global__ __launch_bounds__(256) void k3_local(
    const float* __restrict__ lqi, const float* __restrict__ lki, const float* __restrict__ lvi,
    const float* __restrict__ qw, const float* __restrict__ qb,
    const float* __restrict__ kw, const float* __restrict__ kb,
    const float* __restrict__ vw, const float* __restrict__ vb,
    const float* __restrict__ w3, const float* __restrict__ b3,
    const float* __restrict__ w4, const float* __restrict__ b4,
    float* __restrict__ out)
{
    // 4-channel chunk halo tiles: [ch][row -1..4][col -1..64]
    __shared__ float sq[4][6][66];
    __shared__ float sk[4][6][66];
    __shared__ float sv[4][6][66];
    const int t = threadIdx.x;
    const int w = t & 63;
    const int rr = t >> 6;         // 0..3 output row within tile
    const int bx = blockIdx.x;
    const int htile = bx & 15;
    const int bl = bx >> 4;        // b*4+lh
    const int b = bl >> 2;
    const int lh = bl & 3;
    const int h0 = htile * 4;
    const int h = h0 + rr;

    float a[16], lvv[16];
    #pragma unroll
    for (int c0 = 0; c0 < 16; c0 += 4) {
        // ---- stage 4 channels x 6 rows x 66 cols (zero halo) ----
        for (int e = t; e < 4 * 6 * 66; e += 256) {
            const int col = e % 66 - 1;
            const int r   = (e / 66) % 6;
            const int ch  = e / (66 * 6);
            const int hy  = h0 - 1 + r;
            float vq = 0.f, vk = 0.f, vv = 0.f;
            if (col >= 0 && col < 64 && hy >= 0 && hy < 64) {
                const size_t idx = ((size_t)bl * 16 + c0 + ch) * HW + (size_t)hy * 64 + col;
                vq = lqi[idx]; vk = lki[idx]; vv = lvi[idx];
            }
            ((float*)sq)[e] = vq;
            ((float*)sk)[e] = vk;
            ((float*)sv)[e] = vv;
        }
        __syncthreads();
        // ---- 3x3 depthwise from LDS ----
        #pragma unroll
        for (int ch = 0; ch < 4; ++ch) {
            const int cl = c0 + ch;
            float aq = qb[cl], ak = kb[cl], av = vb[cl];
            #pragma unroll
            for (int dy = 0; dy < 3; ++dy) {
                #pragma unroll
                for (int dx = 0; dx < 3; ++dx) {
                    const int wi = cl * 9 + dy * 3 + dx;
                    aq = fmaf(qw[wi], sq[ch][rr + dy][w + dx], aq);
                    ak = fmaf(kw[wi], sk[ch][rr + dy][w + dx], ak);
                    av = fmaf(vw[wi], sv[ch][rr + dy][w + dx], av);
                }
            }
            a[cl] = aq * ak;
            lvv[cl] = av;
        }
        __syncthreads();
    }

    float a2[16];
    #pragma unroll
    for (int o = 0; o < 16; ++o) {
        float acc = b3[o];
        #pragma unroll
        for (int c2 = 0; c2 < 16; ++c2) acc = fmaf(w3[o * 16 + c2], a[c2], acc);
        a2[o] = acc / (1.f + __expf(-acc));    // silu
    }
    float* op = out + ((size_t)b * 128 + lh * 16) * HW + (size_t)h * 64 + w;  // xl at ch 0..63
    #pragma unroll
    for (int o = 0; o < 16; ++o) {
        float acc = b4[o];
        #pragma unroll
        for (int c2 = 0; c2 < 16; ++c2) acc = fmaf(w4[o * 16 + c2], a2[c2], acc);
        const float z = acc * 8.f;             // tanh(a / LD^-0.5)
        const float e2 = __expf(-2.f * fabsf(z));
        float th = (1.f - e2) / (1.f + e2);
        th = copysignf(th, z);
        op[(size_t)o * HW] = th * lvv[o];
    }
}

// ---------------- K4: fc5 (128x128) + residual, in-place on d_out ----------------
__global__ __launch_bounds__(256) void k4_fc5(
    const float* __restrict__ x, const float* __restrict__ w5,
    const float* __restrict__ b5, float* __restrict__ out)
{
    __shared__ float xc[128][64];
    const int t = threadIdx.x;
    const int g = t >> 6;
    const int p = t & 63;
    const int bx = blockIdx.x;
    const int b = bx >> 6;
    const int h = bx & 63;
    float* obase = out + (size_t)b * 128 * HW + h * 64;
    #pragma unroll
    for (int i = 0; i < 32; ++i) {
        int c = g * 32 + i;
        xc[c][p] = obase[(size_t)c * HW + p];
    }
    __syncthreads();
    const int gu = __builtin_amdgcn_readfirstlane(g);
    const float* xrow = x + (size_t)b * 128 * HW + h * 64;
    for (int cc = 0; cc < 2; ++cc) {
        float acc[16];
        #pragma unroll
        for (int r = 0; r < 16; ++r) acc[r] = b5[gu + 64 * cc + 4 * r];
        #pragma unroll 4
        for (int i = 0; i < 128; ++i) {
            float xv = xc[i][p];
            #pragma unroll
            for (int r = 0; r < 16; ++r)
                acc[r] = fmaf(w5[(size_t)(gu + 64 * cc + 4 * r) * 128 + i], xv, acc[r]);
        }
        #pragma unroll
        for (int r = 0; r < 16; ++r) {
            const int o = gu + 64 * cc + 4 * r;
            obase[(size_t)o * HW + p] = xrow[(size_t)o * HW + p] + acc[r];
        }
    }
}

extern "C" void kernel_launch(void* const* d_in, const int* in_sizes, int n_in,
                              void* d_out, int out_size, void* d_ws, size_t ws_size,
                              hipStream_t stream) {
    const float* x  = (const float*)d_in[0];
    const float* ng = (const float*)d_in[1];
    const float* nb = (const float*)d_in[2];
    const float* w1 = (const float*)d_in[3];
    const float* b1 = (const float*)d_in[4];
    const float* w2 = (const float*)d_in[5];
    const float* b2 = (const float*)d_in[6];
    const float* qw = (const float*)d_in[7];
    const float* qb = (const float*)d_in[8];
    const float* kw = (const float*)d_in[9];
    const float* kb = (const float*)d_in[10];
    const float* vw = (const float*)d_in[11];
    const float* vb = (const float*)d_in[12];
    const float* w3 = (const float*)d_in[13];
    const float* b3 = (const float*)d_in[14];
    const float* w4 = (const float*)d_in[15];
    const float* b4 = (const float*)d_in[16];
    const float* w5 = (const float*)d_in[17];
    const float* b5 = (const float*)d_in[18];
    float* out = (float*)d_out;
    float* ws  = (float*)d_ws;

    float* gq  = ws;                    // 8388608 floats  [b][gh][cg][n]
    float* gkp = gq  + 8388608;         // 131072          [b][gh][m][cg]
    float* gvp = gkp + 131072;          // 131072
    float* lqi = gvp + 131072;          // 8388608         [b][lh][cl][h][w]
    float* lki = lqi + 8388608;
    float* lvi = lki + 8388608;

    hipMemsetAsync(gkp, 0, 2 * 131072 * sizeof(float), stream);
    k1_ln_fc<<<2048, 256, 0, stream>>>(x, ng, nb, w1, b1, w2, b2,
                                       gq, gkp, gvp, lqi, lki, lvi);
    k2_attn<<<2048, 256, 0, stream>>>(gq, gkp, gvp, out);
    k3_local<<<2048, 256, 0, stream>>>(lqi, lki, lvi, qw, qb, kw, kb, vw, vb,
                                       w3, b3, w4, b4, out);
    k4_fc5<<<2048, 256, 0, stream>>>(x, w5, b5, out);
}

// Round 4
// 448.915 us; speedup vs baseline: 1.7422x; 1.5730x over previous
//
#include <hip/hip_runtime.h>
#include <cstddef>

#define HW 4096

typedef short bf16x8 __attribute__((ext_vector_type(8)));
typedef float f32x4 __attribute__((ext_vector_type(4)));
typedef unsigned int u32x4 __attribute__((ext_vector_type(4)));

__device__ __forceinline__ unsigned short f2bf(float f) {
    unsigned u = __builtin_bit_cast(unsigned, f);
    u += 0x7fffu + ((u >> 16) & 1u);
    return (unsigned short)(u >> 16);
}

// ---------------- prep: fp32 -> bf16 weights ----------------
__global__ __launch_bounds__(256) void kprep(
    const float* __restrict__ w1, const float* __restrict__ w2, const float* __restrict__ w5,
    const float* __restrict__ b1, const float* __restrict__ b2,
    unsigned short* __restrict__ wcat, unsigned short* __restrict__ wb5,
    float* __restrict__ bcat)
{
    const int i = blockIdx.x * 256 + threadIdx.x;
    if (i < 384 * 64) {
        const int r = i >> 6;
        wcat[i] = f2bf(r < 192 ? w2[i] : w1[i - 192 * 64]);
    }
    if (i < 128 * 128) wb5[i] = f2bf(w5[i]);
    if (i < 384) bcat[i] = (i < 192) ? b2[i] : b1[i - 192];
}

// ---------------- K1: LayerNorm + fc1/fc2 via MFMA + pooled K/V ----------------
__global__ __launch_bounds__(256) void k1_ln_fc(
    const float* __restrict__ x, const float* __restrict__ ng, const float* __restrict__ nb,
    const unsigned short* __restrict__ wcat, const float* __restrict__ bcat,
    float* __restrict__ gq, float* __restrict__ gkp, float* __restrict__ gvp,
    float* __restrict__ lqi, float* __restrict__ lki, float* __restrict__ lvi)
{
    __shared__ unsigned short xnT[64 * 128];   // [pixel][c] bf16, XOR-swizzled
    __shared__ float red[2][4][64];
    const int t = threadIdx.x;
    const int g = t >> 6;          // wave id
    const int p = t & 63;
    const int bx = blockIdx.x;
    const int b = bx >> 6;
    const int h = bx & 63;
    const float* xrow = x + (size_t)b * 128 * HW + h * 64;

    float v[32];
    float s1 = 0.f, s2 = 0.f;
    #pragma unroll
    for (int i = 0; i < 32; ++i) {
        const int c = g * 32 + i;
        const float vv = xrow[(size_t)c * HW + p];
        v[i] = vv; s1 += vv; s2 += vv * vv;
    }
    red[0][g][p] = s1; red[1][g][p] = s2;
    __syncthreads();
    const float m   = (red[0][0][p] + red[0][1][p] + red[0][2][p] + red[0][3][p]) * (1.f / 128.f);
    const float var = (red[1][0][p] + red[1][1][p] + red[1][2][p] + red[1][3][p]) * (1.f / 128.f) - m * m;
    const float rstd = rsqrtf(var + 1e-5f);

    #pragma unroll
    for (int j = 0; j < 4; ++j) {
        u32x4 pk;
        #pragma unroll
        for (int q = 0; q < 4; ++q) {
            const int i0 = j * 8 + q * 2;
            const int c0 = g * 32 + i0;
            const float f0 = (v[i0]     - m) * rstd * ng[c0]     + nb[c0];
            const float f1 = (v[i0 + 1] - m) * rstd * ng[c0 + 1] + nb[c0 + 1];
            pk[q] = (unsigned)f2bf(f0) | ((unsigned)f2bf(f1) << 16);
        }
        const int colu = (g * 32 + j * 8) ^ ((p & 7) * 8);
        *reinterpret_cast<u32x4*>(&xnT[p * 128 + colu]) = pk;
    }
    __syncthreads();

    const int wid = g;
    const int lg = p >> 4, lr = p & 15;
    const int kbase = (wid >= 2) ? 64 : 0;

    bf16x8 afr[4][2];
    #pragma unroll
    for (int mt = 0; mt < 4; ++mt)
        #pragma unroll
        for (int kc = 0; kc < 2; ++kc) {
            const int pix = mt * 16 + lr;
            const int colu = (kbase + kc * 32 + lg * 8) ^ ((pix & 7) * 8);
            afr[mt][kc] = *reinterpret_cast<const bf16x8*>(&xnT[pix * 128 + colu]);
        }

    const int nbase = wid * 96;
    #pragma unroll
    for (int nt = 0; nt < 6; ++nt) {
        const int o0 = nbase + nt * 16;
        const int o  = o0 + lr;
        const float bias = bcat[o];
        f32x4 acc[4];
        #pragma unroll
        for (int mt = 0; mt < 4; ++mt) acc[mt] = f32x4{bias, bias, bias, bias};
        #pragma unroll
        for (int kc = 0; kc < 2; ++kc) {
            const bf16x8 bfr = *reinterpret_cast<const bf16x8*>(&wcat[(size_t)o * 64 + kc * 32 + lg * 8]);
            #pragma unroll
            for (int mt = 0; mt < 4; ++mt)
                acc[mt] = __builtin_amdgcn_mfma_f32_16x16x32_bf16(afr[mt][kc], bfr, acc[mt], 0, 0, 0);
        }
        if (o0 < 256) {
            float* dst;
            if (o0 < 192) {
                const int cc = o0 >> 6;
                const int lh = (o0 & 63) >> 4;
                float* base = (cc == 0) ? lqi : (cc == 1) ? lki : lvi;
                dst = base + (((size_t)b * 4 + lh) * 16) * HW;
            } else {
                const int gh = (o0 - 192) >> 4;
                dst = gq + (((size_t)b * 4 + gh) * 16) * HW;
            }
            #pragma unroll
            for (int mt = 0; mt < 4; ++mt)
                *reinterpret_cast<f32x4*>(&dst[(size_t)lr * HW + h * 64 + mt * 16 + lg * 4]) = acc[mt];
        } else {
            const int kvsel = (o0 - 256) >> 6;
            const int gh = ((o0 - 256) & 63) >> 4;
            float* dst = (kvsel ? gvp : gkp) + (((size_t)b * 4 + gh) * 64 + (h >> 3) * 8) * 16;
            #pragma unroll
            for (int mt = 0; mt < 4; ++mt) {
                float s = acc[mt][0] + acc[mt][1] + acc[mt][2] + acc[mt][3];
                s += __shfl_xor(s, 16);
                if (!(p & 16))
                    atomicAdd(&dst[(2 * mt + (lg >> 1)) * 16 + lr], s * (1.f / 64.f));
            }
        }
    }
}

// ---------------- K2: global attention (64 pooled tokens) ----------------
__global__ __launch_bounds__(256) void k2_attn(
    const float* __restrict__ gq, const float* __restrict__ gkp,
    const float* __restrict__ gvp, float* __restrict__ out)
{
    const int t = threadIdx.x;
    const int bx = blockIdx.x;
    const int tile = bx & 15;
    const int bg = bx >> 4;
    const int b = bg >> 2;
    const int gh = bg & 3;
    const int n = tile * 256 + t;
    const float* qp = gq + (size_t)bg * 16 * HW + n;
    float q[16];
    #pragma unroll
    for (int cg = 0; cg < 16; ++cg) q[cg] = qp[(size_t)cg * HW] * 0.125f;
    const float* kbase = gkp + (size_t)bg * 64 * 16;
    float s[64];
    #pragma unroll
    for (int mm = 0; mm < 64; ++mm) {
        const float* kr = kbase + mm * 16;
        float a = 0.f;
        #pragma unroll
        for (int cg = 0; cg < 16; ++cg) a = fmaf(q[cg], kr[cg], a);
        s[mm] = a;
    }
    float mx = s[0];
    #pragma unroll
    for (int mm = 1; mm < 64; ++mm) mx = fmaxf(mx, s[mm]);
    float sum = 0.f;
    #pragma unroll
    for (int mm = 0; mm < 64; ++mm) { float e = __expf(s[mm] - mx); s[mm] = e; sum += e; }
    const float rs = 1.f / sum;
    const float* vbase = gvp + (size_t)bg * 64 * 16;
    float acc[16];
    #pragma unroll
    for (int cg = 0; cg < 16; ++cg) acc[cg] = 0.f;
    #pragma unroll
    for (int mm = 0; mm < 64; ++mm) {
        const float pm = s[mm];
        const float* vr = vbase + mm * 16;
        #pragma unroll
        for (int cg = 0; cg < 16; ++cg) acc[cg] = fmaf(pm, vr[cg], acc[cg]);
    }
    float* op = out + ((size_t)b * 128 + 64 + gh * 16) * HW + n;
    #pragma unroll
    for (int cg = 0; cg < 16; ++cg) op[(size_t)cg * HW] = acc[cg] * rs;
}

// ---------------- K3: local branch (dwconv3x3 + gated mix), LDS halo tiles ----------------
__global__ __launch_bounds__(256) void k3_local(
    const float* __restrict__ lqi, const float* __restrict__ lki, const float* __restrict__ lvi,
    const float* __restrict__ qw, const float* __restrict__ qb,
    const float* __restrict__ kw, const float* __restrict__ kb,
    const float* __restrict__ vw, const float* __restrict__ vb,
    const float* __restrict__ w3, const float* __restrict__ b3,
    const float* __restrict__ w4, const float* __restrict__ b4,
    float* __restrict__ out)
{
    __shared__ float sq[4][6][66];
    __shared__ float sk[4][6][66];
    __shared__ float sv[4][6][66];
    const int t = threadIdx.x;
    const int w = t & 63;
    const int rr = t >> 6;
    const int bx = blockIdx.x;
    const int htile = bx & 15;
    const int bl = bx >> 4;
    const int b = bl >> 2;
    const int lh = bl & 3;
    const int h0 = htile * 4;
    const int h = h0 + rr;

    float a[16], lvv[16];
    #pragma unroll
    for (int c0 = 0; c0 < 16; c0 += 4) {
        for (int e = t; e < 4 * 6 * 66; e += 256) {
            const int col = e % 66 - 1;
            const int r   = (e / 66) % 6;
            const int ch  = e / (66 * 6);
            const int hy  = h0 - 1 + r;
            float vq = 0.f, vk = 0.f, vv = 0.f;
            if (col >= 0 && col < 64 && hy >= 0 && hy < 64) {
                const size_t idx = ((size_t)bl * 16 + c0 + ch) * HW + (size_t)hy * 64 + col;
                vq = lqi[idx]; vk = lki[idx]; vv = lvi[idx];
            }
            ((float*)sq)[e] = vq;
            ((float*)sk)[e] = vk;
            ((float*)sv)[e] = vv;
        }
        __syncthreads();
        #pragma unroll
        for (int ch = 0; ch < 4; ++ch) {
            const int cl = c0 + ch;
            float aq = qb[cl], ak = kb[cl], av = vb[cl];
            #pragma unroll
            for (int dy = 0; dy < 3; ++dy) {
                #pragma unroll
                for (int dx = 0; dx < 3; ++dx) {
                    const int wi = cl * 9 + dy * 3 + dx;
                    aq = fmaf(qw[wi], sq[ch][rr + dy][w + dx], aq);
                    ak = fmaf(kw[wi], sk[ch][rr + dy][w + dx], ak);
                    av = fmaf(vw[wi], sv[ch][rr + dy][w + dx], av);
                }
            }
            a[cl] = aq * ak;
            lvv[cl] = av;
        }
        __syncthreads();
    }

    float a2[16];
    #pragma unroll
    for (int o = 0; o < 16; ++o) {
        float acc = b3[o];
        #pragma unroll
        for (int c2 = 0; c2 < 16; ++c2) acc = fmaf(w3[o * 16 + c2], a[c2], acc);
        a2[o] = acc / (1.f + __expf(-acc));
    }
    float* op = out + ((size_t)b * 128 + lh * 16) * HW + (size_t)h * 64 + w;
    #pragma unroll
    for (int o = 0; o < 16; ++o) {
        float acc = b4[o];
        #pragma unroll
        for (int c2 = 0; c2 < 16; ++c2) acc = fmaf(w4[o * 16 + c2], a2[c2], acc);
        const float z = acc * 8.f;
        const float e2 = __expf(-2.f * fabsf(z));
        float th = (1.f - e2) / (1.f + e2);
        th = copysignf(th, z);
        op[(size_t)o * HW] = th * lvv[o];
    }
}

// ---------------- K4: fc5 (128x128) via MFMA + residual, in-place ----------------
__global__ __launch_bounds__(256) void k4_fc5(
    const float* __restrict__ x, const unsigned short* __restrict__ wb5,
    const float* __restrict__ b5, float* __restrict__ out)
{
    __shared__ unsigned short xcT[64 * 128];
    const int t = threadIdx.x;
    const int g = t >> 6, p = t & 63;
    const int bx = blockIdx.x;
    const int b = bx >> 6, h = bx & 63;
    float* obase = out + (size_t)b * 128 * HW + h * 64;

    float v[32];
    #pragma unroll
    for (int i = 0; i < 32; ++i) v[i] = obase[(size_t)(g * 32 + i) * HW + p];
    #pragma unroll
    for (int j = 0; j < 4; ++j) {
        u32x4 pk;
        #pragma unroll
        for (int q = 0; q < 4; ++q) {
            const int i0 = j * 8 + q * 2;
            pk[q] = (unsigned)f2bf(v[i0]) | ((unsigned)f2bf(v[i0 + 1]) << 16);
        }
        const int colu = (g * 32 + j * 8) ^ ((p & 7) * 8);
        *reinterpret_cast<u32x4*>(&xcT[p * 128 + colu]) = pk;
    }
    __syncthreads();

    const int wid = g, lg = p >> 4, lr = p & 15;
    bf16x8 afr[4][4];
    #pragma unroll
    for (int mt = 0; mt < 4; ++mt)
        #pragma unroll
        for (int kc = 0; kc < 4; ++kc) {
            const int pix = mt * 16 + lr;
            const int colu = (kc * 32 + lg * 8) ^ ((pix & 7) * 8);
            afr[mt][kc] = *reinterpret_cast<const bf16x8*>(&xcT[pix * 128 + colu]);
        }
    const float* xrow = x + (size_t)b * 128 * HW + h * 64;
    #pragma unroll
    for (int nt = 0; nt < 2; ++nt) {
        const int o = wid * 32 + nt * 16 + lr;
        const float bias = b5[o];
        f32x4 acc[4];
        #pragma unroll
        for (int mt = 0; mt < 4; ++mt) acc[mt] = f32x4{bias, bias, bias, bias};
        #pragma unroll
        for (int kc = 0; kc < 4; ++kc) {
            const bf16x8 bfr = *reinterpret_cast<const bf16x8*>(&wb5[(size_t)o * 128 + kc * 32 + lg * 8]);
            #pragma unroll
            for (int mt = 0; mt < 4; ++mt)
                acc[mt] = __builtin_amdgcn_mfma_f32_16x16x32_bf16(afr[mt][kc], bfr, acc[mt], 0, 0, 0);
        }
        #pragma unroll
        for (int mt = 0; mt < 4; ++mt) {
            const size_t off = (size_t)o * HW + mt * 16 + lg * 4;
            const f32x4 xr = *reinterpret_cast<const f32x4*>(&xrow[off]);
            const f32x4 r = acc[mt] + xr;
            *reinterpret_cast<f32x4*>(&obase[off]) = r;
        }
    }
}

extern "C" void kernel_launch(void* const* d_in, const int* in_sizes, int n_in,
                              void* d_out, int out_size, void* d_ws, size_t ws_size,
                              hipStream_t stream) {
    const float* x  = (const float*)d_in[0];
    const float* ng = (const float*)d_in[1];
    const float* nb = (const float*)d_in[2];
    const float* w1 = (const float*)d_in[3];
    const float* b1 = (const float*)d_in[4];
    const float* w2 = (const float*)d_in[5];
    const float* b2 = (const float*)d_in[6];
    const float* qw = (const float*)d_in[7];
    const float* qb = (const float*)d_in[8];
    const float* kw = (const float*)d_in[9];
    const float* kb = (const float*)d_in[10];
    const float* vw = (const float*)d_in[11];
    const float* vb = (const float*)d_in[12];
    const float* w3 = (const float*)d_in[13];
    const float* b3 = (const float*)d_in[14];
    const float* w4 = (const float*)d_in[15];
    const float* b4 = (const float*)d_in[16];
    const float* w5 = (const float*)d_in[17];
    const float* b5 = (const float*)d_in[18];
    float* out = (float*)d_out;
    float* ws  = (float*)d_ws;

    float* gq  = ws;                    // 8388608 floats  [b][gh][cg][n]
    float* gkp = gq  + 8388608;         // 131072          [b][gh][m][cg]
    float* gvp = gkp + 131072;          // 131072
    float* lqi = gvp + 131072;          // 8388608         [b][lh][cl][h][w]
    float* lki = lqi + 8388608;
    float* lvi = lki + 8388608;
    float* wend = lvi + 8388608;
    unsigned short* wcat = (unsigned short*)wend;        // 384*64 bf16 (rows 0..191=w2, 192..383=w1)
    unsigned short* wb5  = wcat + 384 * 64;              // 128*128 bf16
    float* bcat = (float*)(wb5 + 128 * 128);             // 384 f32 (b2|b1)

    kprep<<<96, 256, 0, stream>>>(w1, w2, w5, b1, b2, wcat, wb5, bcat);
    hipMemsetAsync(gkp, 0, 2 * 131072 * sizeof(float), stream);
    k1_ln_fc<<<2048, 256, 0, stream>>>(x, ng, nb, wcat, bcat,
                                       gq, gkp, gvp, lqi, lki, lvi);
    k2_attn<<<2048, 256, 0, stream>>>(gq, gkp, gvp, out);
    k3_local<<<2048, 256, 0, stream>>>(lqi, lki, lvi, qw, qb, kw, kb, vw, vb,
                                       w3, b3, w4, b4, out);
    k4_fc5<<<2048, 256, 0, stream>>>(x, wb5, b5, out);
}